// Round 3
// baseline (449.675 us; speedup 1.0000x reference)
//
#include <hip/hip_runtime.h>
#include <hip/hip_bf16.h>

// ---------------------------------------------------------------------------
// MessagePassingModel: N=10000 atoms, E=160000 edges, NC=9 SH channels,
// F=32 features, NB=16 radial basis, NITER=3.
// Float tensor dtype (bf16 vs fp32) is SNIFFED at runtime from the positions
// buffer: reading fp32 data as bf16 yields huge/NaN low-half values with
// near-certainty over 64 samples, while genuine bf16 positions are |v|<~20.
// All kernels branch (wave-uniformly) on the sniffed flag; per-iteration
// weight slices are passed as ELEMENT offsets so byte addressing stays
// dtype-correct. Compute is fp32 throughout.
// ---------------------------------------------------------------------------

#define NITER 3

__device__ __forceinline__ float b2f(const __hip_bfloat16 v) { return __bfloat162float(v); }

template <bool F32>
__device__ __forceinline__ float ldf(const void* p, long i) {
    if constexpr (F32) return ((const float*)p)[i];
    else return __bfloat162float(((const __hip_bfloat16*)p)[i]);
}
template <bool F32>
__device__ __forceinline__ void stf(void* p, long i, float v) {
    if constexpr (F32) ((float*)p)[i] = v;
    else ((__hip_bfloat16*)p)[i] = __float2bfloat16(v);
}

// Analytic real-Gaunt coefficients for l<=2:
#define KC0 0.28209479177387814f   // 1/(2 sqrt(pi))
#define KG1 0.21850968611841584f   // sqrt(15/pi)/10
#define KG2 0.12615662610100802f   // sqrt(5/pi)/10
#define KG3 0.18022375157287861f   // sqrt(5/pi)/7
#define KG4 0.09011187578643931f   // sqrt(5/pi)/14
#define KG5 0.15607834722743988f   // sqrt(15/pi)/14

// --- K-1: dtype sniff -------------------------------------------------------
__global__ void sniff_kernel(const void* __restrict__ pos, int* __restrict__ flag) {
    if (blockIdx.x == 0 && threadIdx.x == 0) {
        const __hip_bfloat16* p = (const __hip_bfloat16*)pos;
        int isf32 = 0;
        for (int k = 0; k < 64; k++) {
            float v = b2f(p[k]);
            if (!(fabsf(v) < 1.0e6f)) isf32 = 1;   // NaN also trips this
        }
        *flag = isf32;
    }
}

// --- K1: x[:,0,:] = embed[an], rest 0 --------------------------------------
template <bool F32>
__device__ void init_x_impl(const int* __restrict__ an, const void* __restrict__ embed,
                            float* __restrict__ x, int N) {
    int idx = blockIdx.x * blockDim.x + threadIdx.x;
    if (idx >= N * 288) return;
    int n = idx / 288, rem = idx % 288;
    float val = 0.0f;
    if (rem < 32) val = ldf<F32>(embed, an[n] * 32 + rem);
    x[idx] = val;
}
__global__ void init_x_kernel(const int* an, const void* embed, float* x, int N,
                              const int* __restrict__ flag) {
    if (*flag) init_x_impl<true>(an, embed, x, N);
    else       init_x_impl<false>(an, embed, x, N);
}

// --- K2: y = x --------------------------------------------------------------
__global__ void copy_kernel(const float4* __restrict__ a, float4* __restrict__ b, int n) {
    int i = blockIdx.x * blockDim.x + threadIdx.x;
    int stride = gridDim.x * blockDim.x;
    for (; i < n; i += stride) b[i] = a[i];
}

// --- K3: edge message + scatter-add (half-wave of 32 lanes = F per edge) ----
template <bool F32>
__device__ void edge_impl(const float* __restrict__ x, float* __restrict__ y,
                          const void* __restrict__ pos,
                          const int* __restrict__ srcI, const int* __restrict__ dstI,
                          const void* __restrict__ Wb, long wOff, int E) {
    int f  = threadIdx.x & 31;
    int hw = (blockIdx.x * blockDim.x + threadIdx.x) >> 5;
    int nhw = gridDim.x * (blockDim.x >> 5);
    float w0[16], w1[16], w2[16];
    #pragma unroll
    for (int n = 0; n < 16; n++) {
        w0[n] = ldf<F32>(Wb, wOff + (0*16 + n)*32 + f);
        w1[n] = ldf<F32>(Wb, wOff + (1*16 + n)*32 + f);
        w2[n] = ldf<F32>(Wb, wOff + (2*16 + n)*32 + f);
    }
    const float BIN[16] = {1.f,15.f,105.f,455.f,1365.f,3003.f,5005.f,6435.f,
                           6435.f,5005.f,3003.f,1365.f,455.f,105.f,15.f,1.f};
    for (int e = hw; e < E; e += nhw) {
        int s = srcI[e], d = dstI[e];
        float dx = ldf<F32>(pos, s*3+0) - ldf<F32>(pos, d*3+0);
        float dy = ldf<F32>(pos, s*3+1) - ldf<F32>(pos, d*3+1);
        float dz = ldf<F32>(pos, s*3+2) - ldf<F32>(pos, d*3+2);
        float r2 = dx*dx + dy*dy + dz*dz + 1e-12f;
        if (r2 >= 16.0f) continue;           // t >= 1 -> fc = 0, no message
        float r  = sqrtf(r2);
        float t  = r * 0.25f;
        float t2 = t * t;
        float fc = expf(-t2 / (1.0f - t2));
        float u = 1.0f / (1.0f + r);
        float v = 1.0f - u;
        float up = 1.0f;
        float vp[16];
        vp[0] = 1.0f;
        #pragma unroll
        for (int k = 1; k < 16; k++) vp[k] = vp[k-1] * v;
        float rw0 = 0.f, rw1 = 0.f, rw2 = 0.f;
        #pragma unroll
        for (int n = 0; n < 16; n++) {
            float rn = BIN[n] * up * vp[15-n] * fc;
            up *= u;
            rw0 = fmaf(rn, w0[n], rw0);
            rw1 = fmaf(rn, w1[n], rw1);
            rw2 = fmaf(rn, w2[n], rw2);
        }
        float ir = 1.0f / r;
        float ux = dx*ir, uy = dy*ir, uz = dz*ir;
        const float c0 = 0.28209479177387814f, c1 = 0.4886025119029199f;
        const float c2a = 1.0925484305920792f, c2b = 0.31539156525252005f, c2c = 0.5462742152960396f;
        float B0 = c0*rw0;
        float B1 = c1*uy*rw1, B2 = c1*uz*rw1, B3 = c1*ux*rw1;
        float B4 = c2a*ux*uy*rw2, B5 = c2a*uy*uz*rw2;
        float B6 = c2b*(3.0f*uz*uz - 1.0f)*rw2;
        float B7 = c2a*ux*uz*rw2, B8 = c2c*(ux*ux - uy*uy)*rw2;
        const float* xp = x + s*288 + f;
        float X0 = xp[0],   X1 = xp[32],  X2 = xp[64],  X3 = xp[96],  X4 = xp[128];
        float X5 = xp[160], X6 = xp[192], X7 = xp[224], X8 = xp[256];
        float* yp = y + d*288 + f;
        float m;
        m = KC0*(X0*B0 + X1*B1 + X2*B2 + X3*B3 + X4*B4 + X5*B5 + X6*B6 + X7*B7 + X8*B8);
        unsafeAtomicAdd(yp + 0, m);
        m = KC0*(X0*B1 + X1*B0) + KG1*(X3*B4 + X4*B3 + X2*B5 + X5*B2)
          - KG2*(X1*B6 + X6*B1) - KG1*(X1*B8 + X8*B1);
        unsafeAtomicAdd(yp + 32, m);
        m = KC0*(X0*B2 + X2*B0) + KG1*(X1*B5 + X5*B1 + X3*B7 + X7*B3)
          + 2.0f*KG2*(X2*B6 + X6*B2);
        unsafeAtomicAdd(yp + 64, m);
        m = KC0*(X0*B3 + X3*B0) + KG1*(X1*B4 + X4*B1 + X2*B7 + X7*B2)
          - KG2*(X3*B6 + X6*B3) + KG1*(X3*B8 + X8*B3);
        unsafeAtomicAdd(yp + 96, m);
        m = KC0*(X0*B4 + X4*B0) + KG1*(X1*B3 + X3*B1) + KG5*(X5*B7 + X7*B5)
          - KG3*(X4*B6 + X6*B4);
        unsafeAtomicAdd(yp + 128, m);
        m = KC0*(X0*B5 + X5*B0) + KG1*(X1*B2 + X2*B1) + KG5*(X4*B7 + X7*B4)
          + KG4*(X5*B6 + X6*B5) - KG5*(X5*B8 + X8*B5);
        unsafeAtomicAdd(yp + 160, m);
        m = KC0*(X0*B6 + X6*B0) - KG2*X1*B1 + 2.0f*KG2*X2*B2 - KG2*X3*B3
          - KG3*X4*B4 + KG4*X5*B5 + KG3*X6*B6 + KG4*X7*B7 - KG3*X8*B8;
        unsafeAtomicAdd(yp + 192, m);
        m = KC0*(X0*B7 + X7*B0) + KG1*(X2*B3 + X3*B2) + KG5*(X4*B5 + X5*B4)
          + KG4*(X6*B7 + X7*B6) + KG5*(X7*B8 + X8*B7);
        unsafeAtomicAdd(yp + 224, m);
        m = KC0*(X0*B8 + X8*B0) - KG1*X1*B1 + KG1*X3*B3 - KG5*X5*B5 + KG5*X7*B7
          - KG3*(X6*B8 + X8*B6);
        unsafeAtomicAdd(yp + 256, m);
    }
}
__global__ __launch_bounds__(256) void edge_kernel(
        const float* x, float* y, const void* pos,
        const int* srcI, const int* dstI, const void* Wb, long wOff, int E,
        const int* __restrict__ flag) {
    if (*flag) edge_impl<true>(x, y, pos, srcI, dstI, Wb, wOff, E);
    else       edge_impl<false>(x, y, pos, srcI, dstI, Wb, wOff, E);
}

// --- K4: x += dense2(silu(dense1(y))) (half-wave of 32 lanes = G per atom) --
template <bool F32>
__device__ void atom_impl(float* __restrict__ x, const float* __restrict__ y,
                          const void* __restrict__ W1, const void* __restrict__ b1,
                          const void* __restrict__ W2, const void* __restrict__ b2,
                          long wOff, long bOff, int N,
                          float* W1s, float* W2s, float* b1s, float* b2s) {
    for (int idx = threadIdx.x; idx < 3072; idx += 256) {
        W1s[idx] = ldf<F32>(W1, wOff + idx);
        W2s[idx] = ldf<F32>(W2, wOff + idx);
    }
    if (threadIdx.x < 32) {
        b1s[threadIdx.x] = ldf<F32>(b1, bOff + threadIdx.x);
        b2s[threadIdx.x] = ldf<F32>(b2, bOff + threadIdx.x);
    }
    __syncthreads();
    int g  = threadIdx.x & 31;
    int hw = (blockIdx.x * blockDim.x + threadIdx.x) >> 5;
    int nhw = gridDim.x * (blockDim.x >> 5);
    const int DEGc[9] = {0,1,1,1,2,2,2,2,2};
    for (int n = hw; n < N; n += nhw) {
        const float* yb = y + n*288;
        float yv[9], sv[9];
        #pragma unroll
        for (int c = 0; c < 9; c++) yv[c] = yb[c*32 + g];
        #pragma unroll
        for (int c = 0; c < 9; c++) {
            const float* Wcol = W1s + DEGc[c]*1024;
            float acc = (c == 0) ? b1s[g] : 0.0f;
            #pragma unroll
            for (int fi = 0; fi < 32; fi++)
                acc = fmaf(__shfl(yv[c], fi, 32), Wcol[fi*32 + g], acc);
            sv[c] = acc / (1.0f + expf(-acc));   // silu
        }
        float* xb = x + n*288;
        #pragma unroll
        for (int c = 0; c < 9; c++) {
            const float* Wcol = W2s + DEGc[c]*1024;
            float acc = (c == 0) ? b2s[g] : 0.0f;
            #pragma unroll
            for (int fi = 0; fi < 32; fi++)
                acc = fmaf(__shfl(sv[c], fi, 32), Wcol[fi*32 + g], acc);
            xb[c*32 + g] += acc;
        }
    }
}
__global__ __launch_bounds__(256) void atom_kernel(
        float* x, const float* y, const void* W1, const void* b1,
        const void* W2, const void* b2, long wOff, long bOff, int N,
        const int* __restrict__ flag) {
    __shared__ float W1s[3*32*32];
    __shared__ float W2s[3*32*32];
    __shared__ float b1s[32], b2s[32];
    if (*flag) atom_impl<true>(x, y, W1, b1, W2, b2, wOff, bOff, N, W1s, W2s, b1s, b2s);
    else       atom_impl<false>(x, y, W1, b1, W2, b2, wOff, bOff, N, W1s, W2s, b1s, b2s);
}

// --- K5: readout (mono, dip) ------------------------------------------------
template <bool F32>
__device__ void readout_impl(const float* __restrict__ x,
        const int* __restrict__ an, const void* __restrict__ pos,
        const void* __restrict__ Wt00, const void* __restrict__ Wt11,
        const void* __restrict__ Wmono, const void* __restrict__ eb,
        void* __restrict__ out, int N) {
    int n = blockIdx.x * blockDim.x + threadIdx.x;
    if (n >= N) return;
    const float* xb = x + n*288;
    float q[4] = {0.f, 0.f, 0.f, 0.f};
    for (int f = 0; f < 32; f++) {
        float xv = xb[f];
        #pragma unroll
        for (int j = 0; j < 4; j++) q[j] = fmaf(xv, ldf<F32>(Wt00, f*4 + j), q[j]);
    }
    float ebv = ldf<F32>(eb, an[n]);
    #pragma unroll
    for (int m = 0; m < 4; m++) {
        float acc = ebv;
        #pragma unroll
        for (int j = 0; j < 4; j++) acc = fmaf(q[j], ldf<F32>(Wmono, j*4 + m), acc);
        stf<F32>(out, n*4 + m, acc);
    }
    #pragma unroll
    for (int c = 0; c < 3; c++) {
        float pc = ldf<F32>(pos, n*3 + c);
        const float* xc = xb + (1 + c)*32;
        float dq[4] = {0.f, 0.f, 0.f, 0.f};
        for (int f = 0; f < 32; f++) {
            float xv = xc[f];
            #pragma unroll
            for (int m = 0; m < 4; m++) dq[m] = fmaf(xv, ldf<F32>(Wt11, f*4 + m), dq[m]);
        }
        #pragma unroll
        for (int m = 0; m < 4; m++) {
            float v = dq[m];
            v = v / (1.0f + expf(-v));                 // silu
            v = fminf(fmaxf(v, -0.3f), 0.3f);          // clip
            stf<F32>(out, N*4 + n*12 + c*4 + m, v + pc);
        }
    }
}
__global__ void readout_kernel(const float* x, const int* an, const void* pos,
        const void* Wt00, const void* Wt11, const void* Wmono, const void* eb,
        void* out, int N, const int* __restrict__ flag) {
    if (*flag) readout_impl<true>(x, an, pos, Wt00, Wt11, Wmono, eb, out, N);
    else       readout_impl<false>(x, an, pos, Wt00, Wt11, Wmono, eb, out, N);
}

extern "C" void kernel_launch(void* const* d_in, const int* in_sizes, int n_in,
                              void* d_out, int out_size, void* d_ws, size_t ws_size,
                              hipStream_t stream) {
    const int* an    = (const int*)d_in[0];
    const void* pos  = d_in[1];
    const int* dstI  = (const int*)d_in[2];
    const int* srcI  = (const int*)d_in[3];
    const void* embed= d_in[4];
    const void* Wb   = d_in[5];
    const void* W1   = d_in[6];
    const void* b1   = d_in[7];
    const void* W2   = d_in[8];
    const void* b2   = d_in[9];
    const void* Wt00 = d_in[10];
    const void* Wt11 = d_in[11];
    const void* Wmono= d_in[12];
    const void* eb   = d_in[13];
    int N = in_sizes[0];
    int E = in_sizes[2];

    // workspace: flag (16B slot) + x + y (N*288 fp32 each) = 23 MB + 16 B
    int* flag = (int*)d_ws;
    float* x  = (float*)((char*)d_ws + 16);
    float* y  = x + (size_t)N * 288;

    sniff_kernel<<<1, 64, 0, stream>>>(pos, flag);
    init_x_kernel<<<(N*288 + 255)/256, 256, 0, stream>>>(an, embed, x, N, flag);
    for (int i = 0; i < NITER; i++) {
        copy_kernel<<<512, 256, 0, stream>>>((const float4*)x, (float4*)y, N*72);
        edge_kernel<<<2048, 256, 0, stream>>>(x, y, pos, srcI, dstI,
                                              Wb, (long)i*3*16*32, E, flag);
        atom_kernel<<<512, 256, 0, stream>>>(x, y, W1, b1, W2, b2,
                                             (long)i*3*1024, (long)i*32, N, flag);
    }
    readout_kernel<<<(N + 255)/256, 256, 0, stream>>>(x, an, pos, Wt00, Wt11, Wmono, eb,
                                                      d_out, N, flag);
}